// Round 1
// baseline (3024.645 us; speedup 1.0000x reference)
//
#include <hip/hip_runtime.h>
#include <math.h>

#define NN 20000
#define NE 320000
#define ET (NE + NN)
#define FIN 17
#define DD 64
#define DOUTC 32
#define NMIDL 18
#define SLOPE 0.2f
#define BN_EPS 1e-5f

// ---------------- preprocessing: CSR by dst ----------------

__global__ void k_init(int* __restrict__ deg, float* __restrict__ s0, float* __restrict__ s1) {
    int i = blockIdx.x * blockDim.x + threadIdx.x;
    if (i < NN) deg[i] = 1;              // self-loop
    if (i < 128) { s0[i] = 0.f; s1[i] = 0.f; }
}

__global__ void k_hist(const int* __restrict__ dst, int* __restrict__ deg) {
    int i = blockIdx.x * blockDim.x + threadIdx.x;
    if (i < NE) atomicAdd(&deg[dst[i]], 1);
}

__global__ __launch_bounds__(1024) void k_scan(const int* __restrict__ deg,
                                               int* __restrict__ row_ptr,
                                               int* __restrict__ cursor) {
    __shared__ int sarr[1024];
    int t = threadIdx.x;
    const int CH = 20;  // 1024*20 >= 20000
    int base = t * CH;
    int sum = 0;
    for (int j = 0; j < CH; ++j) {
        int idx = base + j;
        if (idx < NN) sum += deg[idx];
    }
    sarr[t] = sum;
    __syncthreads();
    for (int off = 1; off < 1024; off <<= 1) {
        int v = (t >= off) ? sarr[t - off] : 0;
        __syncthreads();
        sarr[t] += v;
        __syncthreads();
    }
    int run = sarr[t] - sum;  // exclusive prefix
    for (int j = 0; j < CH; ++j) {
        int idx = base + j;
        if (idx < NN) {
            row_ptr[idx] = run;
            cursor[idx] = run;
            run += deg[idx];
        }
    }
    if (t == 0) row_ptr[NN] = ET;
}

__global__ void k_scatter(const int* __restrict__ src, const int* __restrict__ dst,
                          int* __restrict__ cursor, int* __restrict__ edge_src) {
    int i = blockIdx.x * blockDim.x + threadIdx.x;
    if (i < NE) {
        int d = dst[i];
        int pos = atomicAdd(&cursor[d], 1);
        edge_src[pos] = src[i];
    } else if (i < ET) {
        int v = i - NE;
        int pos = atomicAdd(&cursor[v], 1);
        edge_src[pos] = v;
    }
}

// ---------------- fused dual GEMM: xl = h@Wl+bl, xr = h@Wr+br ----------------
// dcols in {128, 64}; din in {17, 64}. Each thread: 2 nodes x 4 cols x {l,r}.

__global__ __launch_bounds__(256) void k_gemm(const float* __restrict__ hin, int din, int dcols,
                                              const float* __restrict__ Wl, const float* __restrict__ bl,
                                              const float* __restrict__ Wr, const float* __restrict__ br,
                                              float* __restrict__ xl, float* __restrict__ xr) {
    __shared__ float sW[2 * 64 * 128];   // Wl | Wr, padded rows zeroed
    __shared__ float sh[2048];           // node tile, row stride sp
    int tid = threadIdx.x;
    int sp = (din + 3) & ~3;             // padded K (17->20, 64->64)
    int wtot = sp * dcols;
    int wvalid = din * dcols;
    for (int i = tid; i < wtot; i += 256) {
        sW[i]        = (i < wvalid) ? Wl[i] : 0.f;
        sW[wtot + i] = (i < wvalid) ? Wr[i] : 0.f;
    }
    int qc = dcols >> 2;                 // col quads
    int c4 = (tid % qc) * 4;
    int jg = tid / qc;                   // node-pair group
    int ntile = (256 / qc) * 2;          // 16 (dcols=128) or 32 (dcols=64)
    float4 b_l = *(const float4*)&bl[c4];
    float4 b_r = *(const float4*)&br[c4];
    __syncthreads();

    for (int base = blockIdx.x * ntile; base < NN; base += gridDim.x * ntile) {
        for (int i = tid; i < ntile * sp; i += 256) {
            int node = i / sp, k = i % sp;
            sh[i] = (k < din) ? hin[(base + node) * din + k] : 0.f;
        }
        __syncthreads();
        float4 al0 = {0,0,0,0}, al1 = {0,0,0,0}, ar0 = {0,0,0,0}, ar1 = {0,0,0,0};
        int r0 = (jg * 2 + 0) * sp, r1 = (jg * 2 + 1) * sp;
        for (int k = 0; k < sp; ++k) {
            float4 wl = *(const float4*)&sW[k * dcols + c4];
            float4 wr = *(const float4*)&sW[wtot + k * dcols + c4];
            float h0 = sh[r0 + k];
            float h1 = sh[r1 + k];
            al0.x += h0 * wl.x; al0.y += h0 * wl.y; al0.z += h0 * wl.z; al0.w += h0 * wl.w;
            al1.x += h1 * wl.x; al1.y += h1 * wl.y; al1.z += h1 * wl.z; al1.w += h1 * wl.w;
            ar0.x += h0 * wr.x; ar0.y += h0 * wr.y; ar0.z += h0 * wr.z; ar0.w += h0 * wr.w;
            ar1.x += h1 * wr.x; ar1.y += h1 * wr.y; ar1.z += h1 * wr.z; ar1.w += h1 * wr.w;
        }
        int n0 = base + jg * 2, n1 = n0 + 1;
        float4 o;
        o.x = al0.x + b_l.x; o.y = al0.y + b_l.y; o.z = al0.z + b_l.z; o.w = al0.w + b_l.w;
        *(float4*)&xl[n0 * dcols + c4] = o;
        o.x = al1.x + b_l.x; o.y = al1.y + b_l.y; o.z = al1.z + b_l.z; o.w = al1.w + b_l.w;
        *(float4*)&xl[n1 * dcols + c4] = o;
        o.x = ar0.x + b_r.x; o.y = ar0.y + b_r.y; o.z = ar0.z + b_r.z; o.w = ar0.w + b_r.w;
        *(float4*)&xr[n0 * dcols + c4] = o;
        o.x = ar1.x + b_r.x; o.y = ar1.y + b_r.y; o.z = ar1.z + b_r.z; o.w = ar1.w + b_r.w;
        *(float4*)&xr[n1 * dcols + c4] = o;
        __syncthreads();
    }
}

// ---------------- edge aggregation: online softmax per (node, head) ----------------
// one wave per (node, head); lane = channel. hc in {64, 32}; row stride = 2*hc.

__global__ __launch_bounds__(256) void k_edge(const float* __restrict__ xl, const float* __restrict__ xr,
                                              const float* __restrict__ att, const float* __restrict__ bias,
                                              const int* __restrict__ row_ptr, const int* __restrict__ edge_src,
                                              float* __restrict__ g, int hc) {
    __shared__ float sres[2][64];
    int wave = threadIdx.x >> 6;
    int lane = threadIdx.x & 63;
    int nodeLocal = wave >> 1;
    int head = wave & 1;
    int node = blockIdx.x * 2 + nodeLocal;
    if (node >= NN) return;
    int rs = 2 * hc;
    bool act = lane < hc;
    float xrv  = act ? xr[node * rs + head * hc + lane] : 0.f;
    float attc = act ? att[head * hc + lane] : 0.f;
    int beg = row_ptr[node], end = row_ptr[node + 1];

    float m = -1e30f, s = 0.f, o = 0.f;
    for (int i = beg; i < end; ++i) {
        int u = edge_src[i];
        float xlv = act ? xl[u * rs + head * hc + lane] : 0.f;
        float t = xlv + xrv;
        t = (t > 0.f) ? t : SLOPE * t;
        float p = t * attc;
        #pragma unroll
        for (int mask = 32; mask; mask >>= 1) p += __shfl_xor(p, mask);
        float newm = fmaxf(m, p);
        float sc = __expf(m - newm);
        float w  = __expf(p - newm);
        s = s * sc + w;
        o = o * sc + w * xlv;
        m = newm;
    }
    float res = o / s;
    if (head == 1 && act) sres[nodeLocal][lane] = res;
    __syncthreads();
    if (head == 0 && act) {
        g[node * hc + lane] = 0.5f * (res + sres[nodeLocal][lane]) + bias[lane];
    }
}

// ---------------- BN stats: sum & sumsq per feature ----------------

__global__ __launch_bounds__(256) void k_stat(const float* __restrict__ g, float* __restrict__ stats, int hc) {
    __shared__ float ls[4][64], ls2[4][64];
    int lane = threadIdx.x & 63;
    int grp  = threadIdx.x >> 6;
    bool act = lane < hc;
    float s = 0.f, s2 = 0.f;
    for (int row = blockIdx.x * 4 + grp; row < NN; row += gridDim.x * 4) {
        float v = act ? g[row * hc + lane] : 0.f;
        s += v; s2 += v * v;
    }
    ls[grp][lane] = s; ls2[grp][lane] = s2;
    __syncthreads();
    if (grp == 0 && act) {
        float ts  = ls[0][lane] + ls[1][lane] + ls[2][lane] + ls[3][lane];
        float ts2 = ls2[0][lane] + ls2[1][lane] + ls2[2][lane] + ls2[3][lane];
        atomicAdd(&stats[lane], ts);
        atomicAdd(&stats[64 + lane], ts2);
    }
}

// ---------------- BN apply + ReLU + optional residual; zero next stats ----------------

__global__ void k_apply(const float* __restrict__ g, const float* __restrict__ stats,
                        const float* __restrict__ gam, const float* __restrict__ bet,
                        const float* __restrict__ hin, float* __restrict__ hout,
                        int hc, int addres, float* __restrict__ statsNext) {
    if (blockIdx.x == 0 && threadIdx.x < 128) statsNext[threadIdx.x] = 0.f;
    int i = blockIdx.x * blockDim.x + threadIdx.x;
    int total = NN * hc;
    if (i >= total) return;
    int c = i & (hc - 1);
    float mu  = stats[c] * (1.f / NN);
    float var = stats[64 + c] * (1.f / NN) - mu * mu;
    float rsd = rsqrtf(var + BN_EPS);
    float v = gam[c] * (g[i] - mu) * rsd + bet[c];
    v = (v > 0.f) ? v : 0.f;
    hout[i] = (addres ? hin[i] : 0.f) + v;
}

// ---------------- final two heads ----------------

__global__ void k_head(const float* __restrict__ h,
                       const float* __restrict__ Wimp, const float* __restrict__ bimp,
                       const float* __restrict__ Wpol, const float* __restrict__ bpol,
                       float* __restrict__ out) {
    int n = blockIdx.x * blockDim.x + threadIdx.x;
    if (n >= NN) return;
    float a1 = bimp[0], a2 = bpol[0];
    for (int k = 0; k < DOUTC; ++k) {
        float hv = h[n * DOUTC + k];
        a1 += hv * Wimp[k];
        a2 += hv * Wpol[k];
    }
    out[n] = a1;
    out[NN + n] = 1.f / (1.f + expf(-a2));
}

// ---------------- launch ----------------

extern "C" void kernel_launch(void* const* d_in, const int* in_sizes, int n_in,
                              void* d_out, int out_size, void* d_ws, size_t ws_size,
                              hipStream_t stream) {
    const float* x    = (const float*)d_in[0];
    const int*   src  = (const int*)d_in[1];
    const int*   dst  = (const int*)d_in[2];
    const float* W0l  = (const float*)d_in[3];
    const float* b0l  = (const float*)d_in[4];
    const float* W0r  = (const float*)d_in[5];
    const float* b0r  = (const float*)d_in[6];
    const float* att0 = (const float*)d_in[7];
    const float* bias0= (const float*)d_in[8];
    const float* g0   = (const float*)d_in[9];
    const float* be0  = (const float*)d_in[10];
    const float* Wml  = (const float*)d_in[11];
    const float* bml  = (const float*)d_in[12];
    const float* Wmr  = (const float*)d_in[13];
    const float* bmr  = (const float*)d_in[14];
    const float* attm = (const float*)d_in[15];
    const float* biasm= (const float*)d_in[16];
    const float* gm   = (const float*)d_in[17];
    const float* bem  = (const float*)d_in[18];
    const float* WLl  = (const float*)d_in[19];
    const float* bLl  = (const float*)d_in[20];
    const float* WLr  = (const float*)d_in[21];
    const float* bLr  = (const float*)d_in[22];
    const float* attL = (const float*)d_in[23];
    const float* biasL= (const float*)d_in[24];
    const float* gL   = (const float*)d_in[25];
    const float* beL  = (const float*)d_in[26];
    const float* Wimp = (const float*)d_in[27];
    const float* bimp = (const float*)d_in[28];
    const float* Wpol = (const float*)d_in[29];
    const float* bpol = (const float*)d_in[30];
    float* out = (float*)d_out;

    char* w = (char*)d_ws;
    size_t off = 0;
    auto alloc = [&](size_t bytes) -> char* {
        char* p = w + off;
        off += (bytes + 511) & ~(size_t)511;
        return p;
    };
    int* deg      = (int*)alloc(NN * 4);
    int* cursor   = (int*)alloc(NN * 4);
    int* row_ptr  = (int*)alloc((NN + 1) * 4);
    int* edge_src = (int*)alloc(ET * 4);
    float* xl   = (float*)alloc((size_t)NN * 128 * 4);
    float* xr   = (float*)alloc((size_t)NN * 128 * 4);
    float* gbuf = (float*)alloc((size_t)NN * 64 * 4);
    float* hbuf = (float*)alloc((size_t)NN * 64 * 4);
    float* hL   = (float*)alloc((size_t)NN * 32 * 4);
    float* sb[2];
    sb[0] = (float*)alloc(512);
    sb[1] = (float*)alloc(512);

    // preprocessing
    k_init<<<(NN + 255) / 256, 256, 0, stream>>>(deg, sb[0], sb[1]);
    k_hist<<<(NE + 255) / 256, 256, 0, stream>>>(dst, deg);
    k_scan<<<1, 1024, 0, stream>>>(deg, row_ptr, cursor);
    k_scatter<<<(ET + 255) / 256, 256, 0, stream>>>(src, dst, cursor, edge_src);

    // layer 0: x [N,17] -> h [N,64]
    k_gemm<<<512, 256, 0, stream>>>(x, FIN, 128, W0l, b0l, W0r, b0r, xl, xr);
    k_edge<<<NN / 2, 256, 0, stream>>>(xl, xr, att0, bias0, row_ptr, edge_src, gbuf, DD);
    k_stat<<<256, 256, 0, stream>>>(gbuf, sb[0], DD);
    k_apply<<<(NN * DD + 255) / 256, 256, 0, stream>>>(gbuf, sb[0], g0, be0, nullptr, hbuf, DD, 0, sb[1]);

    // mid layers
    for (int i = 0; i < NMIDL; ++i) {
        int L = i + 1;
        const float* Wl = Wml + (size_t)i * DD * 128;
        const float* blp = bml + (size_t)i * 128;
        const float* Wr = Wmr + (size_t)i * DD * 128;
        const float* brp = bmr + (size_t)i * 128;
        const float* at = attm + (size_t)i * 128;
        const float* bs = biasm + (size_t)i * DD;
        const float* ga = gm + (size_t)i * DD;
        const float* be = bem + (size_t)i * DD;
        k_gemm<<<512, 256, 0, stream>>>(hbuf, DD, 128, Wl, blp, Wr, brp, xl, xr);
        k_edge<<<NN / 2, 256, 0, stream>>>(xl, xr, at, bs, row_ptr, edge_src, gbuf, DD);
        k_stat<<<256, 256, 0, stream>>>(gbuf, sb[L & 1], DD);
        k_apply<<<(NN * DD + 255) / 256, 256, 0, stream>>>(gbuf, sb[L & 1], ga, be, hbuf, hbuf, DD, 1, sb[(L + 1) & 1]);
    }

    // final layer: h [N,64] -> hL [N,32]
    {
        int L = 19;
        k_gemm<<<512, 256, 0, stream>>>(hbuf, DD, 64, WLl, bLl, WLr, bLr, xl, xr);
        k_edge<<<NN / 2, 256, 0, stream>>>(xl, xr, attL, biasL, row_ptr, edge_src, gbuf, DOUTC);
        k_stat<<<256, 256, 0, stream>>>(gbuf, sb[L & 1], DOUTC);
        k_apply<<<(NN * DOUTC + 255) / 256, 256, 0, stream>>>(gbuf, sb[L & 1], gL, beL, nullptr, hL, DOUTC, 0, sb[(L + 1) & 1]);
    }

    k_head<<<(NN + 255) / 256, 256, 0, stream>>>(hL, Wimp, bimp, Wpol, bpol, out);
}

// Round 2
// 1913.880 us; speedup vs baseline: 1.5804x; 1.5804x over previous
//
#include <hip/hip_runtime.h>
#include <math.h>

#define NN 20000
#define NE 320000
#define ET (NE + NN)
#define FIN 17
#define DD 64
#define DOUTC 32
#define NMIDL 18
#define SLOPE 0.2f
#define BN_EPS 1e-5f

// ---------------- preprocessing: CSR by dst ----------------

__global__ void k_init(int* __restrict__ deg, float* __restrict__ s0, float* __restrict__ s1) {
    int i = blockIdx.x * blockDim.x + threadIdx.x;
    if (i < NN) deg[i] = 1;              // self-loop
    if (i < 128) { s0[i] = 0.f; s1[i] = 0.f; }
}

__global__ void k_hist(const int* __restrict__ dst, int* __restrict__ deg) {
    int i = blockIdx.x * blockDim.x + threadIdx.x;
    if (i < NE) atomicAdd(&deg[dst[i]], 1);
}

__global__ __launch_bounds__(1024) void k_scan(const int* __restrict__ deg,
                                               int* __restrict__ row_ptr,
                                               int* __restrict__ cursor) {
    __shared__ int sarr[1024];
    int t = threadIdx.x;
    const int CH = 20;  // 1024*20 >= 20000
    int base = t * CH;
    int sum = 0;
    for (int j = 0; j < CH; ++j) {
        int idx = base + j;
        if (idx < NN) sum += deg[idx];
    }
    sarr[t] = sum;
    __syncthreads();
    for (int off = 1; off < 1024; off <<= 1) {
        int v = (t >= off) ? sarr[t - off] : 0;
        __syncthreads();
        sarr[t] += v;
        __syncthreads();
    }
    int run = sarr[t] - sum;  // exclusive prefix
    for (int j = 0; j < CH; ++j) {
        int idx = base + j;
        if (idx < NN) {
            row_ptr[idx] = run;
            cursor[idx] = run;
            run += deg[idx];
        }
    }
    if (t == 0) row_ptr[NN] = ET;
}

__global__ void k_scatter(const int* __restrict__ src, const int* __restrict__ dst,
                          int* __restrict__ cursor, int* __restrict__ edge_src) {
    int i = blockIdx.x * blockDim.x + threadIdx.x;
    if (i < NE) {
        int d = dst[i];
        int pos = atomicAdd(&cursor[d], 1);
        edge_src[pos] = src[i];
    } else if (i < ET) {
        int v = i - NE;
        int pos = atomicAdd(&cursor[v], 1);
        edge_src[pos] = v;
    }
}

// ---------------- fused dual GEMM: xl = h@Wl+bl, xr = h@Wr+br ----------------

__global__ __launch_bounds__(256) void k_gemm(const float* __restrict__ hin, int din, int dcols,
                                              const float* __restrict__ Wl, const float* __restrict__ bl,
                                              const float* __restrict__ Wr, const float* __restrict__ br,
                                              float* __restrict__ xl, float* __restrict__ xr) {
    __shared__ float sW[2 * 64 * 128];   // Wl | Wr, padded rows zeroed
    __shared__ float sh[2048];           // node tile, row stride sp
    int tid = threadIdx.x;
    int sp = (din + 3) & ~3;             // padded K (17->20, 64->64)
    int wtot = sp * dcols;
    int wvalid = din * dcols;
    for (int i = tid; i < wtot; i += 256) {
        sW[i]        = (i < wvalid) ? Wl[i] : 0.f;
        sW[wtot + i] = (i < wvalid) ? Wr[i] : 0.f;
    }
    int qc = dcols >> 2;                 // col quads
    int c4 = (tid % qc) * 4;
    int jg = tid / qc;                   // node-pair group
    int ntile = (256 / qc) * 2;          // 16 (dcols=128) or 32 (dcols=64)
    float4 b_l = *(const float4*)&bl[c4];
    float4 b_r = *(const float4*)&br[c4];
    __syncthreads();

    for (int base = blockIdx.x * ntile; base < NN; base += gridDim.x * ntile) {
        for (int i = tid; i < ntile * sp; i += 256) {
            int node = i / sp, k = i % sp;
            sh[i] = (k < din) ? hin[(base + node) * din + k] : 0.f;
        }
        __syncthreads();
        float4 al0 = {0,0,0,0}, al1 = {0,0,0,0}, ar0 = {0,0,0,0}, ar1 = {0,0,0,0};
        int r0 = (jg * 2 + 0) * sp, r1 = (jg * 2 + 1) * sp;
        for (int k = 0; k < sp; ++k) {
            float4 wl = *(const float4*)&sW[k * dcols + c4];
            float4 wr = *(const float4*)&sW[wtot + k * dcols + c4];
            float h0 = sh[r0 + k];
            float h1 = sh[r1 + k];
            al0.x += h0 * wl.x; al0.y += h0 * wl.y; al0.z += h0 * wl.z; al0.w += h0 * wl.w;
            al1.x += h1 * wl.x; al1.y += h1 * wl.y; al1.z += h1 * wl.z; al1.w += h1 * wl.w;
            ar0.x += h0 * wr.x; ar0.y += h0 * wr.y; ar0.z += h0 * wr.z; ar0.w += h0 * wr.w;
            ar1.x += h1 * wr.x; ar1.y += h1 * wr.y; ar1.z += h1 * wr.z; ar1.w += h1 * wr.w;
        }
        int n0 = base + jg * 2, n1 = n0 + 1;
        float4 o;
        o.x = al0.x + b_l.x; o.y = al0.y + b_l.y; o.z = al0.z + b_l.z; o.w = al0.w + b_l.w;
        *(float4*)&xl[n0 * dcols + c4] = o;
        o.x = al1.x + b_l.x; o.y = al1.y + b_l.y; o.z = al1.z + b_l.z; o.w = al1.w + b_l.w;
        *(float4*)&xl[n1 * dcols + c4] = o;
        o.x = ar0.x + b_r.x; o.y = ar0.y + b_r.y; o.z = ar0.z + b_r.z; o.w = ar0.w + b_r.w;
        *(float4*)&xr[n0 * dcols + c4] = o;
        o.x = ar1.x + b_r.x; o.y = ar1.y + b_r.y; o.z = ar1.z + b_r.z; o.w = ar1.w + b_r.w;
        *(float4*)&xr[n1 * dcols + c4] = o;
        __syncthreads();
    }
}

// ---------------- edge aggregation: one wave per node, both heads ----------------
// CPL = channels per lane per head (2 for hc=64, 1 for hc=32).
// Lane layout: lanes 0..31 = head0, lanes 32..63 = head1; lane covers CPL
// consecutive channels (flat offset co = lane*CPL in the 2*hc row).

template<int CPL>
__global__ __launch_bounds__(256) void k_edge2(const float* __restrict__ xl,
                                               const float* __restrict__ xr,
                                               const float* __restrict__ att,
                                               const float* __restrict__ bias,
                                               const int* __restrict__ row_ptr,
                                               const int* __restrict__ edge_src,
                                               float* __restrict__ g) {
    constexpr int HC = CPL * 32;   // channels per head
    constexpr int RS = 2 * HC;     // row stride (both heads)
    int wave = threadIdx.x >> 6, lane = threadIdx.x & 63;
    int node = blockIdx.x * 4 + wave;
    if (node >= NN) return;
    int co = lane * CPL;
    float2 xrv, attc;
    if (CPL == 2) {
        xrv  = *(const float2*)&xr[node * RS + co];
        attc = *(const float2*)&att[co];
    } else {
        xrv.x = xr[node * RS + co]; xrv.y = 0.f;
        attc.x = att[co];           attc.y = 0.f;
    }
    int beg = row_ptr[node], end = row_ptr[node + 1];
    float m = -1e30f, s = 0.f;
    float2 o = {0.f, 0.f};

    for (int cb = beg; cb < end; cb += 64) {
        int idx = cb + lane;
        int eload = edge_src[idx < end ? idx : end - 1];  // per-lane prefetch of up to 64 edges
        int cnt = min(64, end - cb);
        for (int b = 0; b < cnt; b += 4) {
            int nb = min(4, cnt - b);
            float p[4]; float2 xv[4];
            #pragma unroll
            for (int j = 0; j < 4; ++j) {
                int u = __shfl(eload, b + (j < nb ? j : 0));
                float2 v;
                if (CPL == 2) v = *(const float2*)&xl[u * RS + co];
                else { v.x = xl[u * RS + co]; v.y = 0.f; }
                xv[j] = v;
                float tx = v.x + xrv.x, ty = v.y + xrv.y;
                tx = tx > 0.f ? tx : SLOPE * tx;
                ty = ty > 0.f ? ty : SLOPE * ty;
                float pp = tx * attc.x + ty * attc.y;
                #pragma unroll
                for (int msk = 16; msk; msk >>= 1) pp += __shfl_xor(pp, msk);
                p[j] = (j < nb) ? pp : -1e30f;
            }
            float nm = fmaxf(fmaxf(fmaxf(p[0], p[1]), fmaxf(p[2], p[3])), m);
            float sc = __expf(m - nm);
            float w0 = __expf(p[0] - nm), w1 = __expf(p[1] - nm);
            float w2 = __expf(p[2] - nm), w3 = __expf(p[3] - nm);
            s = s * sc + (w0 + w1) + (w2 + w3);
            o.x = o.x * sc + w0 * xv[0].x + w1 * xv[1].x + w2 * xv[2].x + w3 * xv[3].x;
            o.y = o.y * sc + w0 * xv[0].y + w1 * xv[1].y + w2 * xv[2].y + w3 * xv[3].y;
            m = nm;
        }
    }
    float inv = 1.f / s;
    float rx = o.x * inv, ry = o.y * inv;
    float ox = __shfl_xor(rx, 32);
    float oy = __shfl_xor(ry, 32);
    if (lane < 32) {
        if (CPL == 2) {
            float2 bv = *(const float2*)&bias[co];
            float2 outv = { 0.5f * (rx + ox) + bv.x, 0.5f * (ry + oy) + bv.y };
            *(float2*)&g[node * HC + co] = outv;
        } else {
            g[node * HC + co] = 0.5f * (rx + ox) + bias[co];
        }
    }
}

// ---------------- BN stats: sum & sumsq per feature ----------------

__global__ __launch_bounds__(256) void k_stat(const float* __restrict__ g, float* __restrict__ stats, int hc) {
    __shared__ float ls[4][64], ls2[4][64];
    int lane = threadIdx.x & 63;
    int grp  = threadIdx.x >> 6;
    bool act = lane < hc;
    float s = 0.f, s2 = 0.f;
    for (int row = blockIdx.x * 4 + grp; row < NN; row += gridDim.x * 4) {
        float v = act ? g[row * hc + lane] : 0.f;
        s += v; s2 += v * v;
    }
    ls[grp][lane] = s; ls2[grp][lane] = s2;
    __syncthreads();
    if (grp == 0 && act) {
        float ts  = ls[0][lane] + ls[1][lane] + ls[2][lane] + ls[3][lane];
        float ts2 = ls2[0][lane] + ls2[1][lane] + ls2[2][lane] + ls2[3][lane];
        atomicAdd(&stats[lane], ts);
        atomicAdd(&stats[64 + lane], ts2);
    }
}

// ---------------- BN apply + ReLU + optional residual; zero next stats ----------------

__global__ void k_apply(const float* __restrict__ g, const float* __restrict__ stats,
                        const float* __restrict__ gam, const float* __restrict__ bet,
                        const float* __restrict__ hin, float* __restrict__ hout,
                        int hc, int addres, float* __restrict__ statsNext) {
    if (blockIdx.x == 0 && threadIdx.x < 128) statsNext[threadIdx.x] = 0.f;
    int i = blockIdx.x * blockDim.x + threadIdx.x;
    int total = NN * hc;
    if (i >= total) return;
    int c = i & (hc - 1);
    float mu  = stats[c] * (1.f / NN);
    float var = stats[64 + c] * (1.f / NN) - mu * mu;
    float rsd = rsqrtf(var + BN_EPS);
    float v = gam[c] * (g[i] - mu) * rsd + bet[c];
    v = (v > 0.f) ? v : 0.f;
    hout[i] = (addres ? hin[i] : 0.f) + v;
}

// ---------------- final two heads ----------------

__global__ void k_head(const float* __restrict__ h,
                       const float* __restrict__ Wimp, const float* __restrict__ bimp,
                       const float* __restrict__ Wpol, const float* __restrict__ bpol,
                       float* __restrict__ out) {
    int n = blockIdx.x * blockDim.x + threadIdx.x;
    if (n >= NN) return;
    float a1 = bimp[0], a2 = bpol[0];
    for (int k = 0; k < DOUTC; ++k) {
        float hv = h[n * DOUTC + k];
        a1 += hv * Wimp[k];
        a2 += hv * Wpol[k];
    }
    out[n] = a1;
    out[NN + n] = 1.f / (1.f + expf(-a2));
}

// ---------------- launch ----------------

extern "C" void kernel_launch(void* const* d_in, const int* in_sizes, int n_in,
                              void* d_out, int out_size, void* d_ws, size_t ws_size,
                              hipStream_t stream) {
    const float* x    = (const float*)d_in[0];
    const int*   src  = (const int*)d_in[1];
    const int*   dst  = (const int*)d_in[2];
    const float* W0l  = (const float*)d_in[3];
    const float* b0l  = (const float*)d_in[4];
    const float* W0r  = (const float*)d_in[5];
    const float* b0r  = (const float*)d_in[6];
    const float* att0 = (const float*)d_in[7];
    const float* bias0= (const float*)d_in[8];
    const float* g0   = (const float*)d_in[9];
    const float* be0  = (const float*)d_in[10];
    const float* Wml  = (const float*)d_in[11];
    const float* bml  = (const float*)d_in[12];
    const float* Wmr  = (const float*)d_in[13];
    const float* bmr  = (const float*)d_in[14];
    const float* attm = (const float*)d_in[15];
    const float* biasm= (const float*)d_in[16];
    const float* gm   = (const float*)d_in[17];
    const float* bem  = (const float*)d_in[18];
    const float* WLl  = (const float*)d_in[19];
    const float* bLl  = (const float*)d_in[20];
    const float* WLr  = (const float*)d_in[21];
    const float* bLr  = (const float*)d_in[22];
    const float* attL = (const float*)d_in[23];
    const float* biasL= (const float*)d_in[24];
    const float* gL   = (const float*)d_in[25];
    const float* beL  = (const float*)d_in[26];
    const float* Wimp = (const float*)d_in[27];
    const float* bimp = (const float*)d_in[28];
    const float* Wpol = (const float*)d_in[29];
    const float* bpol = (const float*)d_in[30];
    float* out = (float*)d_out;

    char* w = (char*)d_ws;
    size_t off = 0;
    auto alloc = [&](size_t bytes) -> char* {
        char* p = w + off;
        off += (bytes + 511) & ~(size_t)511;
        return p;
    };
    int* deg      = (int*)alloc(NN * 4);
    int* cursor   = (int*)alloc(NN * 4);
    int* row_ptr  = (int*)alloc((NN + 1) * 4);
    int* edge_src = (int*)alloc(ET * 4);
    float* xl   = (float*)alloc((size_t)NN * 128 * 4);
    float* xr   = (float*)alloc((size_t)NN * 128 * 4);
    float* gbuf = (float*)alloc((size_t)NN * 64 * 4);
    float* hbuf = (float*)alloc((size_t)NN * 64 * 4);
    float* hL   = (float*)alloc((size_t)NN * 32 * 4);
    float* sb[2];
    sb[0] = (float*)alloc(512);
    sb[1] = (float*)alloc(512);

    // preprocessing
    k_init<<<(NN + 255) / 256, 256, 0, stream>>>(deg, sb[0], sb[1]);
    k_hist<<<(NE + 255) / 256, 256, 0, stream>>>(dst, deg);
    k_scan<<<1, 1024, 0, stream>>>(deg, row_ptr, cursor);
    k_scatter<<<(ET + 255) / 256, 256, 0, stream>>>(src, dst, cursor, edge_src);

    // layer 0: x [N,17] -> h [N,64]
    k_gemm<<<512, 256, 0, stream>>>(x, FIN, 128, W0l, b0l, W0r, b0r, xl, xr);
    k_edge2<2><<<(NN + 3) / 4, 256, 0, stream>>>(xl, xr, att0, bias0, row_ptr, edge_src, gbuf);
    k_stat<<<256, 256, 0, stream>>>(gbuf, sb[0], DD);
    k_apply<<<(NN * DD + 255) / 256, 256, 0, stream>>>(gbuf, sb[0], g0, be0, nullptr, hbuf, DD, 0, sb[1]);

    // mid layers
    for (int i = 0; i < NMIDL; ++i) {
        int L = i + 1;
        const float* Wl = Wml + (size_t)i * DD * 128;
        const float* blp = bml + (size_t)i * 128;
        const float* Wr = Wmr + (size_t)i * DD * 128;
        const float* brp = bmr + (size_t)i * 128;
        const float* at = attm + (size_t)i * 128;
        const float* bs = biasm + (size_t)i * DD;
        const float* ga = gm + (size_t)i * DD;
        const float* be = bem + (size_t)i * DD;
        k_gemm<<<512, 256, 0, stream>>>(hbuf, DD, 128, Wl, blp, Wr, brp, xl, xr);
        k_edge2<2><<<(NN + 3) / 4, 256, 0, stream>>>(xl, xr, at, bs, row_ptr, edge_src, gbuf);
        k_stat<<<256, 256, 0, stream>>>(gbuf, sb[L & 1], DD);
        k_apply<<<(NN * DD + 255) / 256, 256, 0, stream>>>(gbuf, sb[L & 1], ga, be, hbuf, hbuf, DD, 1, sb[(L + 1) & 1]);
    }

    // final layer: h [N,64] -> hL [N,32]
    {
        int L = 19;
        k_gemm<<<512, 256, 0, stream>>>(hbuf, DD, 64, WLl, bLl, WLr, bLr, xl, xr);
        k_edge2<1><<<(NN + 3) / 4, 256, 0, stream>>>(xl, xr, attL, biasL, row_ptr, edge_src, gbuf);
        k_stat<<<256, 256, 0, stream>>>(gbuf, sb[L & 1], DOUTC);
        k_apply<<<(NN * DOUTC + 255) / 256, 256, 0, stream>>>(gbuf, sb[L & 1], gL, beL, nullptr, hL, DOUTC, 0, sb[(L + 1) & 1]);
    }

    k_head<<<(NN + 255) / 256, 256, 0, stream>>>(hL, Wimp, bimp, Wpol, bpol, out);
}

// Round 3
// 1540.073 us; speedup vs baseline: 1.9640x; 1.2427x over previous
//
#include <hip/hip_runtime.h>
#include <math.h>

#define NN 20000
#define NE 320000
#define ET (NE + NN)
#define FIN 17
#define DD 64
#define DOUTC 32
#define NMIDL 18
#define SLOPE 0.2f
#define BN_EPS 1e-5f

// ---------------- preprocessing: CSR by dst ----------------

__global__ void k_init(int* __restrict__ deg, float* __restrict__ s0, float* __restrict__ s1) {
    int i = blockIdx.x * blockDim.x + threadIdx.x;
    if (i < NN) deg[i] = 1;              // self-loop
    if (i < 128) { s0[i] = 0.f; s1[i] = 0.f; }
}

__global__ void k_hist(const int* __restrict__ dst, int* __restrict__ deg) {
    int i = blockIdx.x * blockDim.x + threadIdx.x;
    if (i < NE) atomicAdd(&deg[dst[i]], 1);
}

__global__ __launch_bounds__(1024) void k_scan(const int* __restrict__ deg,
                                               int* __restrict__ row_ptr,
                                               int* __restrict__ cursor) {
    __shared__ int sarr[1024];
    int t = threadIdx.x;
    const int CH = 20;  // 1024*20 >= 20000
    int base = t * CH;
    int sum = 0;
    for (int j = 0; j < CH; ++j) {
        int idx = base + j;
        if (idx < NN) sum += deg[idx];
    }
    sarr[t] = sum;
    __syncthreads();
    for (int off = 1; off < 1024; off <<= 1) {
        int v = (t >= off) ? sarr[t - off] : 0;
        __syncthreads();
        sarr[t] += v;
        __syncthreads();
    }
    int run = sarr[t] - sum;  // exclusive prefix
    for (int j = 0; j < CH; ++j) {
        int idx = base + j;
        if (idx < NN) {
            row_ptr[idx] = run;
            cursor[idx] = run;
            run += deg[idx];
        }
    }
    if (t == 0) row_ptr[NN] = ET;
}

__global__ void k_scatter(const int* __restrict__ src, const int* __restrict__ dst,
                          int* __restrict__ cursor, int* __restrict__ edge_src) {
    int i = blockIdx.x * blockDim.x + threadIdx.x;
    if (i < NE) {
        int d = dst[i];
        int pos = atomicAdd(&cursor[d], 1);
        edge_src[pos] = src[i];
    } else if (i < ET) {
        int v = i - NE;
        int pos = atomicAdd(&cursor[v], 1);
        edge_src[pos] = v;
    }
}

// ---------------- dual GEMM, LDS-free: W in VGPRs, h row via scalar loads ----------------
// Each lane owns ONE output column of the concat [Wl | Wr] (2*DCOLS cols).
// Each wave handles one node at a time; the h row is wave-uniform -> s_load
// (readfirstlane + __restrict__), inner loop = DIN x v_fmac_f32 v,s,v.

template<int DIN, int DCOLS>
__global__ __launch_bounds__(256) void k_gemm2(const float* __restrict__ hin,
                                               const float* __restrict__ Wl, const float* __restrict__ bl,
                                               const float* __restrict__ Wr, const float* __restrict__ br,
                                               float* __restrict__ xl, float* __restrict__ xr) {
    constexpr int WPN = (2 * DCOLS) / 64;  // waves per node: 4 (DCOLS=128) or 2 (DCOLS=64)
    constexpr int NPI = 4 / WPN;           // nodes per block-iteration: 1 or 2
    int wave = threadIdx.x >> 6, lane = threadIdx.x & 63;
    int cg = wave % WPN;                   // column-group of this wave
    int nsub = wave / WPN;                 // node sub-index within block
    int col = cg * 64 + lane;              // 0 .. 2*DCOLS-1
    bool isl = col < DCOLS;
    const float* W = isl ? Wl : Wr;
    float* xo = isl ? xl : xr;
    int cw = col & (DCOLS - 1);
    float wreg[DIN];
    #pragma unroll
    for (int k = 0; k < DIN; ++k) wreg[k] = W[k * DCOLS + cw];
    float bias = (isl ? bl : br)[cw];

    for (int node0 = blockIdx.x * NPI; node0 < NN; node0 += gridDim.x * NPI) {
        int node = node0 + nsub;
        int nu = __builtin_amdgcn_readfirstlane(node);
        const float* hrow = hin + (size_t)nu * DIN;
        float a0 = 0.f, a1 = 0.f, a2 = 0.f, a3 = 0.f;
        #pragma unroll
        for (int k = 0; k < DIN; k += 4) {
            a0 = fmaf(hrow[k], wreg[k], a0);
            if (k + 1 < DIN) a1 = fmaf(hrow[k + 1], wreg[k + 1], a1);
            if (k + 2 < DIN) a2 = fmaf(hrow[k + 2], wreg[k + 2], a2);
            if (k + 3 < DIN) a3 = fmaf(hrow[k + 3], wreg[k + 3], a3);
        }
        xo[(size_t)node * DCOLS + cw] = ((a0 + a1) + (a2 + a3)) + bias;
    }
}

// ---------------- edge aggregation: one wave per node, both heads ----------------

template<int CPL>
__global__ __launch_bounds__(256) void k_edge2(const float* __restrict__ xl,
                                               const float* __restrict__ xr,
                                               const float* __restrict__ att,
                                               const float* __restrict__ bias,
                                               const int* __restrict__ row_ptr,
                                               const int* __restrict__ edge_src,
                                               float* __restrict__ g) {
    constexpr int HC = CPL * 32;   // channels per head
    constexpr int RS = 2 * HC;     // row stride (both heads)
    int wave = threadIdx.x >> 6, lane = threadIdx.x & 63;
    int node = blockIdx.x * 4 + wave;
    if (node >= NN) return;
    int co = lane * CPL;
    float2 xrv, attc;
    if (CPL == 2) {
        xrv  = *(const float2*)&xr[node * RS + co];
        attc = *(const float2*)&att[co];
    } else {
        xrv.x = xr[node * RS + co]; xrv.y = 0.f;
        attc.x = att[co];           attc.y = 0.f;
    }
    int beg = row_ptr[node], end = row_ptr[node + 1];
    float m = -1e30f, s = 0.f;
    float2 o = {0.f, 0.f};

    for (int cb = beg; cb < end; cb += 64) {
        int idx = cb + lane;
        int eload = edge_src[idx < end ? idx : end - 1];
        int cnt = min(64, end - cb);
        for (int b = 0; b < cnt; b += 4) {
            int nb = min(4, cnt - b);
            float p[4]; float2 xv[4];
            #pragma unroll
            for (int j = 0; j < 4; ++j) {
                int u = __shfl(eload, b + (j < nb ? j : 0));
                float2 v;
                if (CPL == 2) v = *(const float2*)&xl[u * RS + co];
                else { v.x = xl[u * RS + co]; v.y = 0.f; }
                xv[j] = v;
                float tx = v.x + xrv.x, ty = v.y + xrv.y;
                tx = tx > 0.f ? tx : SLOPE * tx;
                ty = ty > 0.f ? ty : SLOPE * ty;
                float pp = tx * attc.x + ty * attc.y;
                #pragma unroll
                for (int msk = 16; msk; msk >>= 1) pp += __shfl_xor(pp, msk);
                p[j] = (j < nb) ? pp : -1e30f;
            }
            float nm = fmaxf(fmaxf(fmaxf(p[0], p[1]), fmaxf(p[2], p[3])), m);
            float sc = __expf(m - nm);
            float w0 = __expf(p[0] - nm), w1 = __expf(p[1] - nm);
            float w2 = __expf(p[2] - nm), w3 = __expf(p[3] - nm);
            s = s * sc + (w0 + w1) + (w2 + w3);
            o.x = o.x * sc + w0 * xv[0].x + w1 * xv[1].x + w2 * xv[2].x + w3 * xv[3].x;
            o.y = o.y * sc + w0 * xv[0].y + w1 * xv[1].y + w2 * xv[2].y + w3 * xv[3].y;
            m = nm;
        }
    }
    float inv = 1.f / s;
    float rx = o.x * inv, ry = o.y * inv;
    float ox = __shfl_xor(rx, 32);
    float oy = __shfl_xor(ry, 32);
    if (lane < 32) {
        if (CPL == 2) {
            float2 bv = *(const float2*)&bias[co];
            float2 outv = { 0.5f * (rx + ox) + bv.x, 0.5f * (ry + oy) + bv.y };
            *(float2*)&g[node * HC + co] = outv;
        } else {
            g[node * HC + co] = 0.5f * (rx + ox) + bias[co];
        }
    }
}

// ---------------- BN stats: sum & sumsq per feature ----------------

__global__ __launch_bounds__(256) void k_stat(const float* __restrict__ g, float* __restrict__ stats, int hc) {
    __shared__ float ls[4][64], ls2[4][64];
    int lane = threadIdx.x & 63;
    int grp  = threadIdx.x >> 6;
    bool act = lane < hc;
    float s = 0.f, s2 = 0.f;
    for (int row = blockIdx.x * 4 + grp; row < NN; row += gridDim.x * 4) {
        float v = act ? g[row * hc + lane] : 0.f;
        s += v; s2 += v * v;
    }
    ls[grp][lane] = s; ls2[grp][lane] = s2;
    __syncthreads();
    if (grp == 0 && act) {
        float ts  = ls[0][lane] + ls[1][lane] + ls[2][lane] + ls[3][lane];
        float ts2 = ls2[0][lane] + ls2[1][lane] + ls2[2][lane] + ls2[3][lane];
        atomicAdd(&stats[lane], ts);
        atomicAdd(&stats[64 + lane], ts2);
    }
}

// ---------------- BN apply + ReLU + optional residual; zero next stats ----------------

__global__ void k_apply(const float* __restrict__ g, const float* __restrict__ stats,
                        const float* __restrict__ gam, const float* __restrict__ bet,
                        const float* __restrict__ hin, float* __restrict__ hout,
                        int hc, int addres, float* __restrict__ statsNext) {
    if (blockIdx.x == 0 && threadIdx.x < 128) statsNext[threadIdx.x] = 0.f;
    int i = blockIdx.x * blockDim.x + threadIdx.x;
    int total = NN * hc;
    if (i >= total) return;
    int c = i & (hc - 1);
    float mu  = stats[c] * (1.f / NN);
    float var = stats[64 + c] * (1.f / NN) - mu * mu;
    float rsd = rsqrtf(var + BN_EPS);
    float v = gam[c] * (g[i] - mu) * rsd + bet[c];
    v = (v > 0.f) ? v : 0.f;
    hout[i] = (addres ? hin[i] : 0.f) + v;
}

// ---------------- final two heads ----------------

__global__ void k_head(const float* __restrict__ h,
                       const float* __restrict__ Wimp, const float* __restrict__ bimp,
                       const float* __restrict__ Wpol, const float* __restrict__ bpol,
                       float* __restrict__ out) {
    int n = blockIdx.x * blockDim.x + threadIdx.x;
    if (n >= NN) return;
    float a1 = bimp[0], a2 = bpol[0];
    for (int k = 0; k < DOUTC; ++k) {
        float hv = h[n * DOUTC + k];
        a1 += hv * Wimp[k];
        a2 += hv * Wpol[k];
    }
    out[n] = a1;
    out[NN + n] = 1.f / (1.f + expf(-a2));
}

// ---------------- launch ----------------

extern "C" void kernel_launch(void* const* d_in, const int* in_sizes, int n_in,
                              void* d_out, int out_size, void* d_ws, size_t ws_size,
                              hipStream_t stream) {
    const float* x    = (const float*)d_in[0];
    const int*   src  = (const int*)d_in[1];
    const int*   dst  = (const int*)d_in[2];
    const float* W0l  = (const float*)d_in[3];
    const float* b0l  = (const float*)d_in[4];
    const float* W0r  = (const float*)d_in[5];
    const float* b0r  = (const float*)d_in[6];
    const float* att0 = (const float*)d_in[7];
    const float* bias0= (const float*)d_in[8];
    const float* g0   = (const float*)d_in[9];
    const float* be0  = (const float*)d_in[10];
    const float* Wml  = (const float*)d_in[11];
    const float* bml  = (const float*)d_in[12];
    const float* Wmr  = (const float*)d_in[13];
    const float* bmr  = (const float*)d_in[14];
    const float* attm = (const float*)d_in[15];
    const float* biasm= (const float*)d_in[16];
    const float* gm   = (const float*)d_in[17];
    const float* bem  = (const float*)d_in[18];
    const float* WLl  = (const float*)d_in[19];
    const float* bLl  = (const float*)d_in[20];
    const float* WLr  = (const float*)d_in[21];
    const float* bLr  = (const float*)d_in[22];
    const float* attL = (const float*)d_in[23];
    const float* biasL= (const float*)d_in[24];
    const float* gL   = (const float*)d_in[25];
    const float* beL  = (const float*)d_in[26];
    const float* Wimp = (const float*)d_in[27];
    const float* bimp = (const float*)d_in[28];
    const float* Wpol = (const float*)d_in[29];
    const float* bpol = (const float*)d_in[30];
    float* out = (float*)d_out;

    char* w = (char*)d_ws;
    size_t off = 0;
    auto alloc = [&](size_t bytes) -> char* {
        char* p = w + off;
        off += (bytes + 511) & ~(size_t)511;
        return p;
    };
    int* deg      = (int*)alloc(NN * 4);
    int* cursor   = (int*)alloc(NN * 4);
    int* row_ptr  = (int*)alloc((NN + 1) * 4);
    int* edge_src = (int*)alloc(ET * 4);
    float* xl   = (float*)alloc((size_t)NN * 128 * 4);
    float* xr   = (float*)alloc((size_t)NN * 128 * 4);
    float* gbuf = (float*)alloc((size_t)NN * 64 * 4);
    float* hbuf = (float*)alloc((size_t)NN * 64 * 4);
    float* hL   = (float*)alloc((size_t)NN * 32 * 4);
    float* sb[2];
    sb[0] = (float*)alloc(512);
    sb[1] = (float*)alloc(512);

    // preprocessing
    k_init<<<(NN + 255) / 256, 256, 0, stream>>>(deg, sb[0], sb[1]);
    k_hist<<<(NE + 255) / 256, 256, 0, stream>>>(dst, deg);
    k_scan<<<1, 1024, 0, stream>>>(deg, row_ptr, cursor);
    k_scatter<<<(ET + 255) / 256, 256, 0, stream>>>(src, dst, cursor, edge_src);

    // layer 0: x [N,17] -> h [N,64]  (per-matrix cols = H*D = 128)
    k_gemm2<FIN, 128><<<1536, 256, 0, stream>>>(x, W0l, b0l, W0r, b0r, xl, xr);
    k_edge2<2><<<(NN + 3) / 4, 256, 0, stream>>>(xl, xr, att0, bias0, row_ptr, edge_src, gbuf);
    k_stat<<<256, 256, 0, stream>>>(gbuf, sb[0], DD);
    k_apply<<<(NN * DD + 255) / 256, 256, 0, stream>>>(gbuf, sb[0], g0, be0, nullptr, hbuf, DD, 0, sb[1]);

    // mid layers
    for (int i = 0; i < NMIDL; ++i) {
        int L = i + 1;
        const float* Wl = Wml + (size_t)i * DD * 128;
        const float* blp = bml + (size_t)i * 128;
        const float* Wr = Wmr + (size_t)i * DD * 128;
        const float* brp = bmr + (size_t)i * 128;
        const float* at = attm + (size_t)i * 128;
        const float* bs = biasm + (size_t)i * DD;
        const float* ga = gm + (size_t)i * DD;
        const float* be = bem + (size_t)i * DD;
        k_gemm2<DD, 128><<<1536, 256, 0, stream>>>(hbuf, Wl, blp, Wr, brp, xl, xr);
        k_edge2<2><<<(NN + 3) / 4, 256, 0, stream>>>(xl, xr, at, bs, row_ptr, edge_src, gbuf);
        k_stat<<<256, 256, 0, stream>>>(gbuf, sb[L & 1], DD);
        k_apply<<<(NN * DD + 255) / 256, 256, 0, stream>>>(gbuf, sb[L & 1], ga, be, hbuf, hbuf, DD, 1, sb[(L + 1) & 1]);
    }

    // final layer: h [N,64] -> hL [N,32]  (per-matrix cols = H*D_OUT = 64)
    {
        int L = 19;
        k_gemm2<DD, 64><<<768, 256, 0, stream>>>(hbuf, WLl, bLl, WLr, bLr, xl, xr);
        k_edge2<1><<<(NN + 3) / 4, 256, 0, stream>>>(xl, xr, attL, biasL, row_ptr, edge_src, gbuf);
        k_stat<<<256, 256, 0, stream>>>(gbuf, sb[L & 1], DOUTC);
        k_apply<<<(NN * DOUTC + 255) / 256, 256, 0, stream>>>(gbuf, sb[L & 1], gL, beL, nullptr, hL, DOUTC, 0, sb[(L + 1) & 1]);
    }

    k_head<<<(NN + 255) / 256, 256, 0, stream>>>(hL, Wimp, bimp, Wpol, bpol, out);
}